// Round 1
// baseline (6613.349 us; speedup 1.0000x reference)
//
#include <hip/hip_runtime.h>
#include <math.h>

#define NN 100000
#define NE 1600000

// ---- order-preserving float<->uint encoding for atomicMax on floats ----
__device__ __forceinline__ unsigned enc_f32(float f) {
    unsigned u = __float_as_uint(f);
    return (u & 0x80000000u) ? ~u : (u | 0x80000000u);
}
__device__ __forceinline__ float dec_f32(unsigned u) {
    unsigned b = (u & 0x80000000u) ? (u & 0x7FFFFFFFu) : ~u;
    return __uint_as_float(b);
}

// ---- fused linear: q = x@Wq+bq, k = x@Wk+bk, v = x@Wv+bv, out = x@Ws+bs ----
// block = NPB nodes * OUT channels; lane c coalesced over W columns and output rows
template<int IN, int OUT, int NPB>
__global__ __launch_bounds__(OUT * NPB)
void linear_qkvs(const float* __restrict__ x,
                 const float* __restrict__ Wq, const float* __restrict__ bq,
                 const float* __restrict__ Wk, const float* __restrict__ bk,
                 const float* __restrict__ Wv, const float* __restrict__ bv,
                 const float* __restrict__ Ws, const float* __restrict__ bs,
                 float* __restrict__ q, float* __restrict__ k,
                 float* __restrict__ v, float* __restrict__ outskip) {
    int t = threadIdx.x;
    int c = t % OUT;
    int nl = t / OUT;
    int node = blockIdx.x * NPB + nl;
    if (node >= NN) return;
    const float* xr = x + (size_t)node * IN;
    float aq = bq[c], ak = bk[c], av = bv[c], as_ = bs[c];
#pragma unroll
    for (int i = 0; i < IN; ++i) {
        float xv = xr[i];
        aq  += xv * Wq[i * OUT + c];
        ak  += xv * Wk[i * OUT + c];
        av  += xv * Wv[i * OUT + c];
        as_ += xv * Ws[i * OUT + c];
    }
    size_t o = (size_t)node * OUT + c;
    q[o] = aq; k[o] = ak; v[o] = av; outskip[o] = as_;
}

// ---- edge scores: s[e] = <q[dst], k[src]> * scale ; segment-max via atomicMax ----
// 16 lanes per edge, float4 loads -> 256B coalesced row fetch
template<int C>
__global__ __launch_bounds__(256)
void edge_scores(const int* __restrict__ ei,
                 const float* __restrict__ q, const float* __restrict__ k,
                 float* __restrict__ scores, unsigned* __restrict__ m_u,
                 float scale) {
    int gt = blockIdx.x * blockDim.x + threadIdx.x;
    int e = gt >> 4;
    int j = gt & 15;
    if (e >= NE) return;
    int src = ei[e];
    int dst = ei[NE + e];
    const float4* qr = (const float4*)(q + (size_t)dst * C);
    const float4* kr = (const float4*)(k + (size_t)src * C);
    float acc = 0.f;
#pragma unroll
    for (int c4 = j; c4 < C / 4; c4 += 16) {
        float4 a = qr[c4];
        float4 b = kr[c4];
        acc += a.x * b.x + a.y * b.y + a.z * b.z + a.w * b.w;
    }
    // reduce across the 16-lane group
    acc += __shfl_xor(acc, 1);
    acc += __shfl_xor(acc, 2);
    acc += __shfl_xor(acc, 4);
    acc += __shfl_xor(acc, 8);
    if (j == 0) {
        float s = acc * scale;
        scores[e] = s;
        atomicMax(&m_u[dst], enc_f32(s));
    }
}

// ---- exp + segment-sum denom ----
__global__ __launch_bounds__(256)
void edge_exp(const int* __restrict__ ei,
              float* __restrict__ scores,
              const unsigned* __restrict__ m_u,
              float* __restrict__ denom) {
    int e = blockIdx.x * blockDim.x + threadIdx.x;
    if (e >= NE) return;
    int dst = ei[NE + e];
    float m = dec_f32(m_u[dst]);
    float w = __expf(scores[e] - m);
    scores[e] = w;
    atomicAdd(&denom[dst], w);
}

// ---- scatter: out[dst] += (w/denom[dst]) * v[src] ----
template<int C>
__global__ __launch_bounds__(256)
void edge_scatter(const int* __restrict__ ei,
                  const float* __restrict__ scores,
                  const float* __restrict__ denom,
                  const float* __restrict__ v,
                  float* __restrict__ out) {
    int gt = blockIdx.x * blockDim.x + threadIdx.x;
    int e = gt >> 4;
    int j = gt & 15;
    if (e >= NE) return;
    int src = ei[e];
    int dst = ei[NE + e];
    float alpha = scores[e] / denom[dst];
    const float4* vr = (const float4*)(v + (size_t)src * C);
    float* orow = out + (size_t)dst * C;
#pragma unroll
    for (int c4 = j; c4 < C / 4; c4 += 16) {
        float4 a = vr[c4];
        atomicAdd(&orow[4 * c4 + 0], alpha * a.x);
        atomicAdd(&orow[4 * c4 + 1], alpha * a.y);
        atomicAdd(&orow[4 * c4 + 2], alpha * a.z);
        atomicAdd(&orow[4 * c4 + 3], alpha * a.w);
    }
}

__global__ __launch_bounds__(256)
void relu_k(float* __restrict__ h, int n) {
    int i = blockIdx.x * blockDim.x + threadIdx.x;
    if (i < n) h[i] = fmaxf(h[i], 0.f);
}

// ---------------- host side ----------------
template<int IN, int OUT, bool RELU>
static void run_layer(const float* xin, const int* ei,
                      const float* const* Wb,   // Wq,bq,Wk,bk,Wv,bv,Ws,bs
                      float* q, float* k, float* v,
                      float* scores, unsigned* m_u, float* denom,
                      float* out, hipStream_t stream) {
    // zero m_u and denom (contiguous in ws)
    hipMemsetAsync(m_u, 0, (size_t)NN * sizeof(unsigned), stream);
    hipMemsetAsync(denom, 0, (size_t)NN * sizeof(float), stream);

    constexpr int NPB = 4;
    dim3 gl((NN + NPB - 1) / NPB);
    linear_qkvs<IN, OUT, NPB><<<gl, OUT * NPB, 0, stream>>>(
        xin, Wb[0], Wb[1], Wb[2], Wb[3], Wb[4], Wb[5], Wb[6], Wb[7],
        q, k, v, out);

    float scale = 1.0f / sqrtf((float)OUT);
    int eb = ((size_t)NE * 16 + 255) / 256;
    edge_scores<OUT><<<eb, 256, 0, stream>>>(ei, q, k, scores, m_u, scale);
    edge_exp<<<(NE + 255) / 256, 256, 0, stream>>>(ei, scores, m_u, denom);
    edge_scatter<OUT><<<eb, 256, 0, stream>>>(ei, scores, denom, v, out);
    if (RELU) {
        int n = NN * OUT;
        relu_k<<<(n + 255) / 256, 256, 0, stream>>>(out, n);
    }
}

extern "C" void kernel_launch(void* const* d_in, const int* in_sizes, int n_in,
                              void* d_out, int out_size, void* d_ws, size_t ws_size,
                              hipStream_t stream) {
    const float* x  = (const float*)d_in[0];
    const int*   ei = (const int*)d_in[1];
    const float* Wb0[8], *Wb1[8], *Wb2[8];
    for (int i = 0; i < 8; ++i) {
        Wb0[i] = (const float*)d_in[2 + i];
        Wb1[i] = (const float*)d_in[10 + i];
        Wb2[i] = (const float*)d_in[18 + i];
    }
    float* out = (float*)d_out;

    char* ws = (char*)d_ws;
    const size_t CMAX = 112;
    size_t off = 0;
    float* q      = (float*)(ws + off); off += (size_t)NN * CMAX * 4;   // 44.8 MB
    float* k      = (float*)(ws + off); off += (size_t)NN * CMAX * 4;
    float* v      = (float*)(ws + off); off += (size_t)NN * CMAX * 4;
    float* h0     = (float*)(ws + off); off += (size_t)NN * 64 * 4;     // 25.6 MB
    float* h1     = (float*)(ws + off); off += (size_t)NN * 64 * 4;
    float* scores = (float*)(ws + off); off += (size_t)NE * 4;          // 6.4 MB
    unsigned* m_u = (unsigned*)(ws + off); off += (size_t)NN * 4;
    float* denom  = (float*)(ws + off); off += (size_t)NN * 4;
    (void)ws_size; (void)in_sizes; (void)n_in; (void)out_size;

    // layer 0: 8 -> 64, ReLU
    run_layer<8, 64, true>(x, ei, Wb0, q, k, v, scores, m_u, denom, h0, stream);
    // layer 1: 64 -> 64, ReLU
    run_layer<64, 64, true>(h0, ei, Wb1, q, k, v, scores, m_u, denom, h1, stream);
    // layer 2: 64 -> 112, no ReLU
    run_layer<64, 112, false>(h1, ei, Wb2, q, k, v, scores, m_u, denom, out, stream);
}

// Round 2
// 1537.385 us; speedup vs baseline: 4.3017x; 4.3017x over previous
//
#include <hip/hip_runtime.h>
#include <math.h>

#define NN 100000
#define NE 1600000

#define SCAN_T 256
#define SCAN_E 1024                       // elements per scan block (4/thread)
#define SCAN_NB ((NN + SCAN_E - 1) / SCAN_E)   // 98

// ---- fused linear: q,k,v,skip ----
template<int IN, int OUT, int NPB>
__global__ __launch_bounds__(OUT * NPB)
void linear_qkvs(const float* __restrict__ x,
                 const float* __restrict__ Wq, const float* __restrict__ bq,
                 const float* __restrict__ Wk, const float* __restrict__ bk,
                 const float* __restrict__ Wv, const float* __restrict__ bv,
                 const float* __restrict__ Ws, const float* __restrict__ bs,
                 float* __restrict__ q, float* __restrict__ k,
                 float* __restrict__ v, float* __restrict__ outskip) {
    int t = threadIdx.x;
    int c = t % OUT;
    int nl = t / OUT;
    int node = blockIdx.x * NPB + nl;
    if (node >= NN) return;
    const float* xr = x + (size_t)node * IN;
    float aq = bq[c], ak = bk[c], av = bv[c], as_ = bs[c];
#pragma unroll
    for (int i = 0; i < IN; ++i) {
        float xv = xr[i];
        aq  += xv * Wq[i * OUT + c];
        ak  += xv * Wk[i * OUT + c];
        av  += xv * Wv[i * OUT + c];
        as_ += xv * Ws[i * OUT + c];
    }
    size_t o = (size_t)node * OUT + c;
    q[o] = aq; k[o] = ak; v[o] = av; outskip[o] = as_;
}

// ---------------- CSR build (once per launch; topology shared by all layers) ----------------
__global__ __launch_bounds__(256)
void hist_k(const int* __restrict__ ei, int* __restrict__ counts) {
    int e = blockIdx.x * blockDim.x + threadIdx.x;
    if (e < NE) atomicAdd(&counts[ei[NE + e]], 1);
}

__global__ __launch_bounds__(SCAN_T)
void scan1(const int* __restrict__ counts, int* __restrict__ offsets,
           int* __restrict__ blocksums) {
    __shared__ int lds[SCAN_T];
    int t = threadIdx.x;
    int base = blockIdx.x * SCAN_E + t * 4;
    int vals[4];
    int s = 0;
#pragma unroll
    for (int j = 0; j < 4; ++j) {
        int idx = base + j;
        vals[j] = (idx < NN) ? counts[idx] : 0;
        s += vals[j];
    }
    lds[t] = s;
    __syncthreads();
    for (int off = 1; off < SCAN_T; off <<= 1) {
        int xx = (t >= off) ? lds[t - off] : 0;
        __syncthreads();
        lds[t] += xx;
        __syncthreads();
    }
    int run = (t > 0) ? lds[t - 1] : 0;
    if (t == SCAN_T - 1) blocksums[blockIdx.x] = lds[t];
#pragma unroll
    for (int j = 0; j < 4; ++j) {
        int idx = base + j;
        if (idx < NN) offsets[idx] = run;
        run += vals[j];
    }
}

__global__ __launch_bounds__(128)
void scan2(int* __restrict__ blocksums) {
    __shared__ int lds[128];
    int t = threadIdx.x;
    lds[t] = (t < SCAN_NB) ? blocksums[t] : 0;
    __syncthreads();
    for (int off = 1; off < 128; off <<= 1) {
        int xx = (t >= off) ? lds[t - off] : 0;
        __syncthreads();
        lds[t] += xx;
        __syncthreads();
    }
    if (t < SCAN_NB) blocksums[t] = (t > 0) ? lds[t - 1] : 0;
}

__global__ __launch_bounds__(256)
void scan3(int* __restrict__ offsets, int* __restrict__ pos,
           const int* __restrict__ blocksums) {
    int i = blockIdx.x * blockDim.x + threadIdx.x;
    if (i < NN) {
        int o = offsets[i] + blocksums[i / SCAN_E];
        offsets[i] = o;
        pos[i] = o;
    }
    if (i == 0) offsets[NN] = NE;
}

__global__ __launch_bounds__(256)
void build_csr(const int* __restrict__ ei, int* __restrict__ pos,
               int* __restrict__ sorted_src) {
    int e = blockIdx.x * blockDim.x + threadIdx.x;
    if (e < NE) {
        int d = ei[NE + e];
        int p = atomicAdd(&pos[d], 1);
        sorted_src[p] = ei[e];
    }
}

// ---------------- fused per-node online-softmax attention gather ----------------
// one wave (64 lanes) per destination node; zero atomics; single coalesced write
template<int C, bool RELU>
__global__ __launch_bounds__(256)
void attn_gather(const int* __restrict__ offsets,
                 const int* __restrict__ sorted_src,
                 const float* __restrict__ q, const float* __restrict__ k,
                 const float* __restrict__ v,
                 float* __restrict__ out, float scale) {
    int wave = (int)((blockIdx.x * blockDim.x + threadIdx.x) >> 6);
    int lane = threadIdx.x & 63;
    if (wave >= NN) return;
    int beg = offsets[wave], end = offsets[wave + 1];

    constexpr int PL = (C + 63) / 64;   // 1 (C=64) or 2 (C=112)
    float qreg[PL], acc[PL];
#pragma unroll
    for (int p = 0; p < PL; ++p) {
        int c = lane + p * 64;
        qreg[p] = (c < C) ? q[(size_t)wave * C + c] : 0.f;
        acc[p] = 0.f;
    }
    float m = -INFINITY, l = 0.f;

    int src_next = (beg < end) ? sorted_src[beg] : 0;
    for (int i = beg; i < end; ++i) {
        int src = src_next;
        if (i + 1 < end) src_next = sorted_src[i + 1];
        float kv[PL], vv[PL];
#pragma unroll
        for (int p = 0; p < PL; ++p) {
            int c = lane + p * 64;
            kv[p] = (c < C) ? k[(size_t)src * C + c] : 0.f;
            vv[p] = (c < C) ? v[(size_t)src * C + c] : 0.f;
        }
        float part = 0.f;
#pragma unroll
        for (int p = 0; p < PL; ++p) part += qreg[p] * kv[p];
        part += __shfl_xor(part, 1);
        part += __shfl_xor(part, 2);
        part += __shfl_xor(part, 4);
        part += __shfl_xor(part, 8);
        part += __shfl_xor(part, 16);
        part += __shfl_xor(part, 32);
        float s = part * scale;
        float mn = fmaxf(m, s);
        float al = __expf(m - mn);   // 1 on first edge? no: exp(-inf)=0, l starts 0 anyway
        float w  = __expf(s - mn);
        l = l * al + w;
#pragma unroll
        for (int p = 0; p < PL; ++p) acc[p] = acc[p] * al + w * vv[p];
        m = mn;
    }

    float inv = (end > beg) ? (1.f / l) : 0.f;
#pragma unroll
    for (int p = 0; p < PL; ++p) {
        int c = lane + p * 64;
        if (c < C) {
            size_t o = (size_t)wave * C + c;
            float r = out[o] + acc[p] * inv;   // out holds the skip term
            out[o] = RELU ? fmaxf(r, 0.f) : r;
        }
    }
}

// ---------------- host side ----------------
template<int IN, int OUT, bool RELU>
static void run_layer(const float* xin,
                      const float* const* Wb,
                      const int* offsets, const int* sorted_src,
                      float* q, float* k, float* v,
                      float* out, hipStream_t stream) {
    constexpr int NPB = 4;
    dim3 gl((NN + NPB - 1) / NPB);
    linear_qkvs<IN, OUT, NPB><<<gl, OUT * NPB, 0, stream>>>(
        xin, Wb[0], Wb[1], Wb[2], Wb[3], Wb[4], Wb[5], Wb[6], Wb[7],
        q, k, v, out);

    float scale = 1.0f / sqrtf((float)OUT);
    int waves_per_block = 256 / 64;
    int gb = (NN + waves_per_block - 1) / waves_per_block;
    attn_gather<OUT, RELU><<<gb, 256, 0, stream>>>(
        offsets, sorted_src, q, k, v, out, scale);
}

extern "C" void kernel_launch(void* const* d_in, const int* in_sizes, int n_in,
                              void* d_out, int out_size, void* d_ws, size_t ws_size,
                              hipStream_t stream) {
    const float* x  = (const float*)d_in[0];
    const int*   ei = (const int*)d_in[1];
    const float* Wb0[8], *Wb1[8], *Wb2[8];
    for (int i = 0; i < 8; ++i) {
        Wb0[i] = (const float*)d_in[2 + i];
        Wb1[i] = (const float*)d_in[10 + i];
        Wb2[i] = (const float*)d_in[18 + i];
    }
    float* out = (float*)d_out;

    char* ws = (char*)d_ws;
    const size_t CMAX = 112;
    size_t off = 0;
    float* q          = (float*)(ws + off); off += (size_t)NN * CMAX * 4;
    float* k          = (float*)(ws + off); off += (size_t)NN * CMAX * 4;
    float* v          = (float*)(ws + off); off += (size_t)NN * CMAX * 4;
    float* h0         = (float*)(ws + off); off += (size_t)NN * 64 * 4;
    float* h1         = (float*)(ws + off); off += (size_t)NN * 64 * 4;
    int*   sorted_src = (int*)(ws + off);   off += (size_t)NE * 4;
    int*   counts     = (int*)(ws + off);   off += (size_t)NN * 4;
    int*   offsets    = (int*)(ws + off);   off += (size_t)(NN + 1) * 4;
    int*   pos        = (int*)(ws + off);   off += (size_t)NN * 4;
    int*   blocksums  = (int*)(ws + off);   off += (size_t)SCAN_NB * 4;
    (void)ws_size; (void)in_sizes; (void)n_in; (void)out_size;

    // ---- build CSR (grouped by dst) once; shared by all 3 layers ----
    hipMemsetAsync(counts, 0, (size_t)NN * sizeof(int), stream);
    hist_k<<<(NE + 255) / 256, 256, 0, stream>>>(ei, counts);
    scan1<<<SCAN_NB, SCAN_T, 0, stream>>>(counts, offsets, blocksums);
    scan2<<<1, 128, 0, stream>>>(blocksums);
    scan3<<<(NN + 255) / 256, 256, 0, stream>>>(offsets, pos, blocksums);
    build_csr<<<(NE + 255) / 256, 256, 0, stream>>>(ei, pos, sorted_src);

    // layer 0: 8 -> 64, ReLU
    run_layer<8, 64, true>(x, Wb0, offsets, sorted_src, q, k, v, h0, stream);
    // layer 1: 64 -> 64, ReLU
    run_layer<64, 64, true>(h0, Wb1, offsets, sorted_src, q, k, v, h1, stream);
    // layer 2: 64 -> 112, no ReLU
    run_layer<64, 112, false>(h1, Wb2, offsets, sorted_src, q, k, v, out, stream);
}